// Round 4
// baseline (952.506 us; speedup 1.0000x reference)
//
#include <hip/hip_runtime.h>

// Problem constants
#define TP 512   // passage length
#define TB 8     // batch
#define TD 256   // input size
#define TH 75    // attn hidden
#define THP 80   // padded attn hidden (float4-friendly, pads zeroed)
#define TO 128   // GRU hidden

typedef _Float16 half_t;
typedef _Float16 half4v __attribute__((ext_vector_type(4)));
typedef _Float16 half8v __attribute__((ext_vector_type(8)));
typedef float    float4v __attribute__((ext_vector_type(4)));

__device__ __forceinline__ float fast_rcp(float x) { return __builtin_amdgcn_rcpf(x); }
__device__ __forceinline__ float fast_tanh(float x) {
    return 1.0f - 2.0f * fast_rcp(1.0f + __expf(2.0f * x));
}
__device__ __forceinline__ float fast_sigmoid(float x) {
    return fast_rcp(1.0f + __expf(-x));
}
__device__ __forceinline__ float f4c(const float4 a, int u) {
    return (u == 0) ? a.x : (u == 1) ? a.y : (u == 2) ? a.z : a.w;
}
// score partial: sum c * rcp(1+exp(2(a+b)));  tanh(x) = 1 - 2*rcp(1+exp(2x))
__device__ __forceinline__ float rterm4(float4 a, float4 b, float4 c) {
    float s;
    s  = c.x * fast_rcp(1.0f + __expf(2.0f * (a.x + b.x)));
    s += c.y * fast_rcp(1.0f + __expf(2.0f * (a.y + b.y)));
    s += c.z * fast_rcp(1.0f + __expf(2.0f * (a.z + b.z)));
    s += c.w * fast_rcp(1.0f + __expf(2.0f * (a.w + b.w)));
    return s;
}

// ---------------- prep: transposes + MFMA A-fragment w_hh -------------------
// wfrag layout: [dir(2)][tile(24)=g*8+m][kt(4)][lane(64)][j(8)] halfs, where
// A-frag (16x16x32_f16): A[mrow=lane&15][k=(lane>>4)*8+j], mrow within tile,
// row_global = g*128 + m*16 + mrow, k_global = kt*32 + (lane>>4)*8 + j.
__global__ __launch_bounds__(256) void prep_kernel(
    const float* __restrict__ Wvp1, const float* __restrict__ Wvp2,
    const float* __restrict__ Wg,   const float* __restrict__ wihf,
    const float* __restrict__ wihb, const float* __restrict__ bihf,
    const float* __restrict__ bihb, const float* __restrict__ whhf,
    const float* __restrict__ whhb,
    float* __restrict__ WTvp, float* __restrict__ WgT,
    float* __restrict__ WihT, float* __restrict__ bihC,
    half_t* __restrict__ wfrag)
{
    int idx = blockIdx.x * 256 + threadIdx.x;
    if (idx < 256 * 160) {                      // WTvp[k][o], o<150 = [Wvp1;Wvp2]
        int k = idx / 160, o = idx - k * 160;
        float vv = 0.0f;
        if (o < 75)       vv = Wvp1[o * 256 + k];
        else if (o < 150) vv = Wvp2[(o - 75) * 256 + k];
        WTvp[idx] = vv;
        return;
    }
    idx -= 256 * 160;
    if (idx < 512 * 512) {                      // WgT[k][o] = Wg[o][k]
        int k = idx >> 9, o = idx & 511;
        WgT[idx] = Wg[o * 512 + k];
        return;
    }
    idx -= 512 * 512;
    if (idx < 512 * 768) {                      // WihT[k][o], o<384 fwd else bwd
        int k = idx / 768, o = idx - k * 768;
        WihT[idx] = (o < 384) ? wihf[o * 512 + k] : wihb[(o - 384) * 512 + k];
        return;
    }
    idx -= 512 * 768;
    if (idx < 768) { bihC[idx] = (idx < 384) ? bihf[idx] : bihb[idx - 384]; return; }
    idx -= 768;
    if (idx < 2 * 24 * 4 * 64 * 8) {
        int d    = idx / 49152;
        int r    = idx - d * 49152;
        int tile = r >> 11;           // /2048
        int rem  = r & 2047;
        int kt   = rem >> 9;          // /512
        int rem2 = rem & 511;
        int lane = rem2 >> 3;
        int j    = rem2 & 7;
        int g = tile >> 3, m = tile & 7;
        int row = g * 128 + m * 16 + (lane & 15);
        int k   = kt * 32 + (lane >> 4) * 8 + j;
        const float* src = d ? whhb : whhf;
        wfrag[idx] = (half_t)src[row * TO + k];
    }
}

// ---------------- Wv1/Wv2 = v @ Wvp{1,2}.T, stored [b][p][80] (pads zero) ----
__global__ __launch_bounds__(256) void wv12_kernel(
    const float* __restrict__ v, const float* __restrict__ WTvp,
    float* __restrict__ Wv1, float* __restrict__ Wv2)
{
    int tid = threadIdx.x;
    int p = blockIdx.x >> 3, b = blockIdx.x & 7;
    __shared__ float vrow[256];
    vrow[tid] = v[blockIdx.x * 256 + tid];   // blockIdx = p*8+b, matches v[p][b][:]
    __syncthreads();
    int ob = (b * TP + p) * THP;
    if (tid < 150) {
        float a0 = 0.f, a1 = 0.f, a2 = 0.f, a3 = 0.f;
        for (int k = 0; k < 256; k += 4) {
            a0 += vrow[k]     * WTvp[(k)     * 160 + tid];
            a1 += vrow[k + 1] * WTvp[(k + 1) * 160 + tid];
            a2 += vrow[k + 2] * WTvp[(k + 2) * 160 + tid];
            a3 += vrow[k + 3] * WTvp[(k + 3) * 160 + tid];
        }
        float acc = (a0 + a1) + (a2 + a3);
        if (tid < 75) Wv1[ob + tid] = acc;
        else          Wv2[ob + tid - 75] = acc;
    } else if (tid < 155) {
        Wv1[ob + 75 + (tid - 150)] = 0.0f;   // zero pads
    } else if (tid < 160) {
        Wv2[ob + 75 + (tid - 155)] = 0.0f;
    }
}

// -------- fused scores -> softmax(i) -> context -> build g=[v,c] ------------
__global__ __launch_bounds__(256) void attn_kernel(
    const float* __restrict__ v,
    const float* __restrict__ Wv1, const float* __restrict__ Wv2,
    const float* __restrict__ vw, float* __restrict__ g)
{
    int tid = threadIdx.x;
    int b  = blockIdx.x >> 7;
    int j0 = (blockIdx.x & 127) * 4;
    __shared__ float wv1j[4 * THP];
    __shared__ float vws[THP];
    __shared__ float sc[4 * TP];

    if (tid < THP) vws[tid] = (tid < TH) ? vw[tid] : 0.0f;
    for (int e = tid; e < 4 * THP; e += 256) {
        int jj = e / THP, k = e - jj * THP;
        wv1j[e] = Wv1[(b * TP + j0 + jj) * THP + k];
    }
    __syncthreads();

    float Csum = 0.0f;
    {
        const float4* c4 = (const float4*)vws;
        for (int kk = 0; kk < 20; ++kk) { float4 c = c4[kk]; Csum += c.x + c.y + c.z + c.w; }
    }

    // ---- scores: sc[jj][i] = Csum - 2 * sum_h vw[h]*rcp(1+exp(2(Wv2+Wv1)))
    for (int rep = 0; rep < 2; ++rep) {
        int i = tid + rep * 256;
        const float4* row4 = (const float4*)(Wv2 + (b * TP + i) * THP);
        float acc[4] = {0.f, 0.f, 0.f, 0.f};
#pragma unroll
        for (int kt = 0; kt < 5; ++kt) {
            float4 r0 = row4[kt * 4 + 0], r1 = row4[kt * 4 + 1];
            float4 r2 = row4[kt * 4 + 2], r3 = row4[kt * 4 + 3];
            const float4* c4 = (const float4*)(vws + kt * 16);
            float4 c0 = c4[0], c1 = c4[1], c2 = c4[2], c3 = c4[3];
#pragma unroll
            for (int jj = 0; jj < 4; ++jj) {
                const float4* w1 = (const float4*)(wv1j + jj * THP + kt * 16);
                acc[jj] += rterm4(r0, w1[0], c0) + rterm4(r1, w1[1], c1)
                         + rterm4(r2, w1[2], c2) + rterm4(r3, w1[3], c3);
            }
        }
#pragma unroll
        for (int jj = 0; jj < 4; ++jj) sc[jj * TP + i] = Csum - 2.0f * acc[jj];
    }
    __syncthreads();

    // ---- softmax over i (axis 0), one wave per jj
    {
        int jj = tid >> 6, l = tid & 63;
        float m = -1e30f;
#pragma unroll
        for (int q = 0; q < 8; ++q) m = fmaxf(m, sc[jj * TP + l + q * 64]);
#pragma unroll
        for (int s = 32; s > 0; s >>= 1) m = fmaxf(m, __shfl_xor(m, s));
        float e[8];
        float sum = 0.0f;
#pragma unroll
        for (int q = 0; q < 8; ++q) { e[q] = __expf(sc[jj * TP + l + q * 64] - m); sum += e[q]; }
#pragma unroll
        for (int s = 32; s > 0; s >>= 1) sum += __shfl_xor(sum, s);
        float inv = fast_rcp(sum);
#pragma unroll
        for (int q = 0; q < 8; ++q) sc[jj * TP + l + q * 64] = e[q] * inv;
    }
    __syncthreads();

    // ---- context: c[j,b,d] = sum_i a[i]*v[i,b,d]; thread owns d = tid
    float acc[4] = {0.f, 0.f, 0.f, 0.f};
    const float* vb = v + b * TD + tid;
    for (int i4 = 0; i4 < TP / 4; ++i4) {
        float4 a0 = ((const float4*)(sc + 0 * TP))[i4];
        float4 a1 = ((const float4*)(sc + 1 * TP))[i4];
        float4 a2 = ((const float4*)(sc + 2 * TP))[i4];
        float4 a3 = ((const float4*)(sc + 3 * TP))[i4];
#pragma unroll
        for (int u = 0; u < 4; ++u) {
            float va = vb[(i4 * 4 + u) * (TB * TD)];
            acc[0] += f4c(a0, u) * va;
            acc[1] += f4c(a1, u) * va;
            acc[2] += f4c(a2, u) * va;
            acc[3] += f4c(a3, u) * va;
        }
    }
#pragma unroll
    for (int jj = 0; jj < 4; ++jj) {
        int base = ((j0 + jj) * TB + b) * 512;
        g[base + tid]       = v[((j0 + jj) * TB + b) * TD + tid];
        g[base + 256 + tid] = acc[jj];
    }
}

// -------- fused gate (sigmoid(g Wg^T)*g) + GRU input projections ------------
__global__ __launch_bounds__(512) void gatexp_kernel(
    const float* __restrict__ g, const float* __restrict__ WgT,
    const float* __restrict__ WihT, const float* __restrict__ bihC,
    float* __restrict__ xpf, float* __restrict__ xpb)
{
    __shared__ float gt[16 * 512];      // row-major original g
    __shared__ float gT[512 * 20];      // transposed, padded stride 20: gT[k*20+r]
    int tid = threadIdx.x;
    int r0 = blockIdx.x * 16;

    const float4* gsrc = (const float4*)(g + r0 * 512);
    for (int e = tid; e < 2048; e += 512) {
        float4 vv = gsrc[e];
        ((float4*)gt)[e] = vv;
        int r = e >> 7, k4 = e & 127;
        gT[(k4 * 4 + 0) * 20 + r] = vv.x;
        gT[(k4 * 4 + 1) * 20 + r] = vv.y;
        gT[(k4 * 4 + 2) * 20 + r] = vv.z;
        gT[(k4 * 4 + 3) * 20 + r] = vv.w;
    }
    __syncthreads();

    int tx = tid & 63, w = tid >> 6;
    int rg = w >> 2;                 // rows rg*8 .. rg*8+7
    int cg = w & 3;

    float acc[8][2];
#pragma unroll
    for (int r = 0; r < 8; ++r) { acc[r][0] = 0.f; acc[r][1] = 0.f; }
    int col = cg * 128 + tx * 2;
    {
        const float* wp = WgT + col;
        const float* gp = gT + rg * 8;
#pragma unroll 4
        for (int k = 0; k < 512; ++k) {
            float2 wv = *(const float2*)wp;
            float4 ga = *(const float4*)gp;
            float4 gb = *(const float4*)(gp + 4);
            acc[0][0] += ga.x * wv.x; acc[0][1] += ga.x * wv.y;
            acc[1][0] += ga.y * wv.x; acc[1][1] += ga.y * wv.y;
            acc[2][0] += ga.z * wv.x; acc[2][1] += ga.z * wv.y;
            acc[3][0] += ga.w * wv.x; acc[3][1] += ga.w * wv.y;
            acc[4][0] += gb.x * wv.x; acc[4][1] += gb.x * wv.y;
            acc[5][0] += gb.y * wv.x; acc[5][1] += gb.y * wv.y;
            acc[6][0] += gb.z * wv.x; acc[6][1] += gb.z * wv.y;
            acc[7][0] += gb.w * wv.x; acc[7][1] += gb.w * wv.y;
            wp += 512; gp += 20;
        }
    }
    float gated[8][2];
#pragma unroll
    for (int r = 0; r < 8; ++r) {
        float2 go = *(const float2*)(gt + (rg * 8 + r) * 512 + col);
        gated[r][0] = fast_sigmoid(acc[r][0]) * go.x;
        gated[r][1] = fast_sigmoid(acc[r][1]) * go.y;
    }
    __syncthreads();
#pragma unroll
    for (int c = 0; c < 2; ++c) {
        float4 p0 = { gated[0][c], gated[1][c], gated[2][c], gated[3][c] };
        float4 p1 = { gated[4][c], gated[5][c], gated[6][c], gated[7][c] };
        *(float4*)(gT + (col + c) * 20 + rg * 8)     = p0;
        *(float4*)(gT + (col + c) * 20 + rg * 8 + 4) = p1;
    }
    __syncthreads();

    float a2[8][3];
#pragma unroll
    for (int r = 0; r < 8; ++r) { a2[r][0] = 0.f; a2[r][1] = 0.f; a2[r][2] = 0.f; }
    int col2 = cg * 192 + tx;
    {
        const float* wp = WihT + col2;
        const float* gp = gT + rg * 8;
#pragma unroll 4
        for (int k = 0; k < 512; ++k) {
            float w0 = wp[0], w1 = wp[64], w2 = wp[128];
            float4 ga = *(const float4*)gp;
            float4 gb = *(const float4*)(gp + 4);
            a2[0][0] += ga.x * w0; a2[0][1] += ga.x * w1; a2[0][2] += ga.x * w2;
            a2[1][0] += ga.y * w0; a2[1][1] += ga.y * w1; a2[1][2] += ga.y * w2;
            a2[2][0] += ga.z * w0; a2[2][1] += ga.z * w1; a2[2][2] += ga.z * w2;
            a2[3][0] += ga.w * w0; a2[3][1] += ga.w * w1; a2[3][2] += ga.w * w2;
            a2[4][0] += gb.x * w0; a2[4][1] += gb.x * w1; a2[4][2] += gb.x * w2;
            a2[5][0] += gb.y * w0; a2[5][1] += gb.y * w1; a2[5][2] += gb.y * w2;
            a2[6][0] += gb.z * w0; a2[6][1] += gb.z * w1; a2[6][2] += gb.z * w2;
            a2[7][0] += gb.w * w0; a2[7][1] += gb.w * w1; a2[7][2] += gb.w * w2;
            wp += 768; gp += 20;
        }
    }
#pragma unroll
    for (int c = 0; c < 3; ++c) {
        int oc = col2 + c * 64;
        float bv = bihC[oc];
        float* dst;
        if (oc < 384) dst = xpf + oc;
        else          dst = xpb + oc - 384;
#pragma unroll
        for (int r = 0; r < 8; ++r) {
            int row = r0 + rg * 8 + r;
            dst[row * 384] = a2[r][c] + bv;
        }
    }
}

// ---------------- GRU recurrence: MFMA batched matvec -----------------------
// One block per direction; 256 threads = 4 waves. Per step:
//   gh(384x8) = W(384x128) @ H(128x8)  via 16x16x32_f16 MFMA, batches = cols.
// Wave w owns output rows o in [32w, 32w+32) for all 3 gates: tiles
// {g*8+2w, g*8+2w+1}. C/D layout: col=lane&15=batch, row=quad*4+reg -> each
// lane gets r,z,n sums for its (o,batch) in-register; h computed in-lane,
// no shuffles, 1 barrier/step. bhh folded into MFMA C-init.
__global__ __launch_bounds__(256, 1) void gru_kernel(
    const float* __restrict__ xpf, const float* __restrict__ xpb,
    const half_t* __restrict__ wfrag,
    const float* __restrict__ bhhf, const float* __restrict__ bhhb,
    float* __restrict__ out)
{
    int tid  = threadIdx.x;
    int dir  = blockIdx.x;
    int lane = tid & 63;
    int w    = tid >> 6;
    int n    = lane & 15;       // batch (valid < 8)
    int quad = lane >> 4;

    const float* xp  = dir ? xpb  : xpf;
    const float* bhh = dir ? bhhb : bhhf;
    float* outp = out + dir * TO;

    // H double buffer: [buf][batch n][k], stride 136 halfs (272 B) per n
    __shared__ half_t Hb[2 * 2176];

    int ob[2] = { 32 * w + quad * 4, 32 * w + 16 + quad * 4 };

    // weight A-fragments: 6 tile-slots (ts = g*2+mi) x 4 k-steps
    half8v wf[6][4];
#pragma unroll
    for (int g = 0; g < 3; ++g)
#pragma unroll
        for (int mi = 0; mi < 2; ++mi) {
            int tile = g * 8 + 2 * w + mi;
#pragma unroll
            for (int kt = 0; kt < 4; ++kt)
                wf[g * 2 + mi][kt] = *(const half8v*)(
                    wfrag + (((dir * 24 + tile) * 4 + kt) * 64 + lane) * 8);
        }

    // bias folded into C-init
    float4v bias4[6];
#pragma unroll
    for (int g = 0; g < 3; ++g)
#pragma unroll
        for (int mi = 0; mi < 2; ++mi) {
            float4v bv;
#pragma unroll
            for (int r = 0; r < 4; ++r) bv[r] = bhh[g * 128 + ob[mi] + r];
            bias4[g * 2 + mi] = bv;
        }

    float hprev[2][4] = {{0.f,0.f,0.f,0.f},{0.f,0.f,0.f,0.f}};

    for (int i = tid; i < 2 * 2176; i += 256) Hb[i] = (half_t)0.0f;

    float4v xA[6], xB[6];
    {   // prefetch s=0
        int t0 = dir ? (TP - 1) : 0;
        if (n < TB) {
#pragma unroll
            for (int g = 0; g < 3; ++g)
#pragma unroll
                for (int mi = 0; mi < 2; ++mi)
                    xA[g * 2 + mi] = *(const float4v*)(
                        xp + (t0 * TB + n) * 384 + g * 128 + ob[mi]);
        }
    }
    __syncthreads();

#define GRU_STEP(S, RD, WRb, XU, XPF) do {                                     \
    int t_  = dir ? (TP - 1 - (S)) : (S);                                      \
    int sp_ = ((S) + 1 < TP) ? (S) + 1 : (S);                                  \
    int tp_ = dir ? (TP - 1 - sp_) : sp_;                                      \
    if (n < TB) {                                                              \
        _Pragma("unroll") for (int g = 0; g < 3; ++g)                          \
        _Pragma("unroll") for (int mi = 0; mi < 2; ++mi)                       \
            XPF[g * 2 + mi] = *(const float4v*)(                               \
                xp + (tp_ * TB + n) * 384 + g * 128 + ob[mi]);                 \
    }                                                                          \
    half8v hf_[4];                                                             \
    _Pragma("unroll") for (int kt = 0; kt < 4; ++kt)                           \
        hf_[kt] = *(const half8v*)(Hb + (RD) * 2176 + n * 136 + kt * 32 + quad * 8); \
    float4v c_[6];                                                             \
    _Pragma("unroll") for (int ts = 0; ts < 6; ++ts) c_[ts] = bias4[ts];       \
    _Pragma("unroll") for (int ts = 0; ts < 6; ++ts)                           \
    _Pragma("unroll") for (int kt = 0; kt < 4; ++kt)                           \
        c_[ts] = __builtin_amdgcn_mfma_f32_16x16x32_f16(wf[ts][kt], hf_[kt], c_[ts], 0, 0, 0); \
    if (n < TB) {                                                              \
        _Pragma("unroll") for (int mi = 0; mi < 2; ++mi) {                     \
            float4v ar = c_[0 + mi], az = c_[2 + mi], an = c_[4 + mi];         \
            float4v xr = XU[0 + mi], xz = XU[2 + mi], xn = XU[4 + mi];         \
            float4v hnew; half4v h16;                                          \
            _Pragma("unroll") for (int r = 0; r < 4; ++r) {                    \
                float rr = fast_sigmoid(xr[r] + ar[r]);                        \
                float zz = fast_sigmoid(xz[r] + az[r]);                        \
                float nn = fast_tanh(xn[r] + rr * an[r]);                      \
                float hv = (1.0f - zz) * nn + zz * hprev[mi][r];               \
                hprev[mi][r] = hv; hnew[r] = hv; h16[r] = (half_t)hv;          \
            }                                                                  \
            *(half4v*)(Hb + (WRb) * 2176 + n * 136 + ob[mi]) = h16;            \
            *(float4v*)(outp + (t_ * TB + n) * 256 + ob[mi]) = hnew;           \
        }                                                                      \
    }                                                                          \
    __syncthreads();                                                           \
} while (0)

    for (int s = 0; s < TP; s += 2) {
        GRU_STEP(s,     0, 1, xA, xB);
        GRU_STEP(s + 1, 1, 0, xB, xA);
    }
#undef GRU_STEP
}

extern "C" void kernel_launch(void* const* d_in, const int* in_sizes, int n_in,
                              void* d_out, int out_size, void* d_ws, size_t ws_size,
                              hipStream_t stream) {
    const float* v    = (const float*)d_in[0];
    const float* Wvp1 = (const float*)d_in[1];
    const float* Wvp2 = (const float*)d_in[2];
    const float* vw   = (const float*)d_in[3];
    const float* Wg   = (const float*)d_in[4];
    const float* wihf = (const float*)d_in[5];
    const float* whhf = (const float*)d_in[6];
    const float* bihf = (const float*)d_in[7];
    const float* bhhf = (const float*)d_in[8];
    const float* wihb = (const float*)d_in[9];
    const float* whhb = (const float*)d_in[10];
    const float* bihb = (const float*)d_in[11];
    const float* bhhb = (const float*)d_in[12];

    float* ws   = (float*)d_ws;
    float* WTvp = ws;                    // 256*160      = 40960
    float* WgT  = WTvp + 40960;          // 512*512      = 262144
    float* WihT = WgT + 262144;          // 512*768      = 393216
    float* bihC = WihT + 393216;         // 768
    float* Wv1  = bihC + 768;            // 8*512*80     = 327680
    float* Wv2  = Wv1 + 327680;          // 327680
    float* g    = Wv2 + 327680;          // 4096*512     = 2097152
    float* xpf  = g + 2097152;           // 4096*384     = 1572864
    float* xpb  = xpf + 1572864;         // 1572864
    half_t* wfrag = (half_t*)(xpb + 1572864);  // 2*24*4*64*8 halfs = 49152 floats
    float* out  = (float*)d_out;

    // prep total idx: 40960+262144+393216+768+98304 = 795392 = 3107*256
    prep_kernel<<<3107, 256, 0, stream>>>(Wvp1, Wvp2, Wg, wihf, wihb, bihf, bihb,
                                          whhf, whhb, WTvp, WgT, WihT, bihC, wfrag);
    wv12_kernel<<<4096, 256, 0, stream>>>(v, WTvp, Wv1, Wv2);
    attn_kernel<<<1024, 256, 0, stream>>>(v, Wv1, Wv2, vw, g);
    gatexp_kernel<<<256, 512, 0, stream>>>(g, WgT, WihT, bihC, xpf, xpb);
    gru_kernel<<<2, 256, 0, stream>>>(xpf, xpb, wfrag, bhhf, bhhb, out);
}

// Round 5
// 624.992 us; speedup vs baseline: 1.5240x; 1.5240x over previous
//
#include <hip/hip_runtime.h>

// Problem constants
#define TP 512   // passage length
#define TB 8     // batch
#define TD 256   // input size
#define TH 75    // attn hidden
#define THP 80   // padded attn hidden (float4-friendly, pads zeroed)
#define TO 128   // GRU hidden

typedef _Float16 half_t;
typedef _Float16 half2v __attribute__((ext_vector_type(2)));
typedef _Float16 half4v __attribute__((ext_vector_type(4)));
typedef _Float16 half8v __attribute__((ext_vector_type(8)));
typedef float    float4v __attribute__((ext_vector_type(4)));

union H8 { half8v v8; half2v v2[4]; };

__device__ __forceinline__ float fast_rcp(float x) { return __builtin_amdgcn_rcpf(x); }
__device__ __forceinline__ float fast_tanh(float x) {
    return 1.0f - 2.0f * fast_rcp(1.0f + __expf(2.0f * x));
}
__device__ __forceinline__ float fast_sigmoid(float x) {
    return fast_rcp(1.0f + __expf(-x));
}
__device__ __forceinline__ float f4c(const float4 a, int u) {
    return (u == 0) ? a.x : (u == 1) ? a.y : (u == 2) ? a.z : a.w;
}
__device__ __forceinline__ float fdot2h(half2v a, half2v b, float c) {
#if __has_builtin(__builtin_amdgcn_fdot2)
    return __builtin_amdgcn_fdot2(a, b, c, false);
#else
    return c + (float)a[0] * (float)b[0] + (float)a[1] * (float)b[1];
#endif
}
// score partial: sum c * rcp(1+exp(2(a+b)));  tanh(x) = 1 - 2*rcp(1+exp(2x))
__device__ __forceinline__ float rterm4(float4 a, float4 b, float4 c) {
    float s;
    s  = c.x * fast_rcp(1.0f + __expf(2.0f * (a.x + b.x)));
    s += c.y * fast_rcp(1.0f + __expf(2.0f * (a.y + b.y)));
    s += c.z * fast_rcp(1.0f + __expf(2.0f * (a.z + b.z)));
    s += c.w * fast_rcp(1.0f + __expf(2.0f * (a.w + b.w)));
    return s;
}

// ---------------- prep: WTvp transpose, f16 B-fragment weights, f16 whh -----
// Wg16B layout [nt(32)][kt(16)][lane(64)][j(8)] halfs = B-frag for
// mfma_f32_16x16x32_f16: B[k = kt*32 + (lane>>4)*8 + j][n = nt*16 + (lane&15)]
// (layout verified end-to-end in R4's correct-but-slow GRU). Wih16B same with
// nt in [0,48), o<384 fwd else bwd. whh16: [dir][(g*128+o)*128+k] f16 (R3 GRU).
__global__ __launch_bounds__(256) void prep_kernel(
    const float* __restrict__ Wvp1, const float* __restrict__ Wvp2,
    const float* __restrict__ Wg,   const float* __restrict__ wihf,
    const float* __restrict__ wihb, const float* __restrict__ bihf,
    const float* __restrict__ bihb, const float* __restrict__ whhf,
    const float* __restrict__ whhb,
    float* __restrict__ WTvp, float* __restrict__ bihC,
    half_t* __restrict__ Wg16B, half_t* __restrict__ Wih16B,
    half_t* __restrict__ whh16)
{
    int idx = blockIdx.x * 256 + threadIdx.x;
    if (idx < 256 * 160) {                      // WTvp[k][o], o<150 = [Wvp1;Wvp2]
        int k = idx / 160, o = idx - k * 160;
        float vv = 0.0f;
        if (o < 75)       vv = Wvp1[o * 256 + k];
        else if (o < 150) vv = Wvp2[(o - 75) * 256 + k];
        WTvp[idx] = vv;
        return;
    }
    idx -= 256 * 160;
    if (idx < 768) { bihC[idx] = (idx < 384) ? bihf[idx] : bihb[idx - 384]; return; }
    idx -= 768;
    if (idx < 262144) {                         // Wg16B
        int j = idx & 7, lane = (idx >> 3) & 63, kt = (idx >> 9) & 15, nt = idx >> 13;
        int o = nt * 16 + (lane & 15);
        int k = kt * 32 + ((lane >> 4) << 3) + j;
        Wg16B[idx] = (half_t)Wg[o * 512 + k];
        return;
    }
    idx -= 262144;
    if (idx < 393216) {                         // Wih16B
        int j = idx & 7, lane = (idx >> 3) & 63, kt = (idx >> 9) & 15, nt = idx >> 13;
        int o = nt * 16 + (lane & 15);
        int k = kt * 32 + ((lane >> 4) << 3) + j;
        Wih16B[idx] = (half_t)((o < 384) ? wihf[o * 512 + k] : wihb[(o - 384) * 512 + k]);
        return;
    }
    idx -= 393216;
    if (idx < 98304) {                          // whh16[dir][(g*128+o)*128+k]
        int d = idx / 49152, i = idx - d * 49152;
        whh16[idx] = (half_t)(d ? whhb[i] : whhf[i]);
    }
}

// ---------------- Wv1/Wv2 = v @ Wvp{1,2}.T, stored [b][p][80] (pads zero) ----
__global__ __launch_bounds__(256) void wv12_kernel(
    const float* __restrict__ v, const float* __restrict__ WTvp,
    float* __restrict__ Wv1, float* __restrict__ Wv2)
{
    int tid = threadIdx.x;
    int p = blockIdx.x >> 3, b = blockIdx.x & 7;
    __shared__ float vrow[256];
    vrow[tid] = v[blockIdx.x * 256 + tid];   // blockIdx = p*8+b, matches v[p][b][:]
    __syncthreads();
    int ob = (b * TP + p) * THP;
    if (tid < 150) {
        float a0 = 0.f, a1 = 0.f, a2 = 0.f, a3 = 0.f;
        for (int k = 0; k < 256; k += 4) {
            a0 += vrow[k]     * WTvp[(k)     * 160 + tid];
            a1 += vrow[k + 1] * WTvp[(k + 1) * 160 + tid];
            a2 += vrow[k + 2] * WTvp[(k + 2) * 160 + tid];
            a3 += vrow[k + 3] * WTvp[(k + 3) * 160 + tid];
        }
        float acc = (a0 + a1) + (a2 + a3);
        if (tid < 75) Wv1[ob + tid] = acc;
        else          Wv2[ob + tid - 75] = acc;
    } else if (tid < 155) {
        Wv1[ob + 75 + (tid - 150)] = 0.0f;   // zero pads
    } else if (tid < 160) {
        Wv2[ob + 75 + (tid - 155)] = 0.0f;
    }
}

// -------- fused scores -> softmax(i) -> context -> build g16=[v,c] (f16) ----
__global__ __launch_bounds__(256) void attn_kernel(
    const float* __restrict__ v,
    const float* __restrict__ Wv1, const float* __restrict__ Wv2,
    const float* __restrict__ vw, half_t* __restrict__ g16)
{
    int tid = threadIdx.x;
    int b  = blockIdx.x >> 7;
    int j0 = (blockIdx.x & 127) * 4;
    __shared__ float wv1j[4 * THP];
    __shared__ float vws[THP];
    __shared__ float sc[4 * TP];

    if (tid < THP) vws[tid] = (tid < TH) ? vw[tid] : 0.0f;
    for (int e = tid; e < 4 * THP; e += 256) {
        int jj = e / THP, k = e - jj * THP;
        wv1j[e] = Wv1[(b * TP + j0 + jj) * THP + k];
    }
    __syncthreads();

    float Csum = 0.0f;
    {
        const float4* c4 = (const float4*)vws;
        for (int kk = 0; kk < 20; ++kk) { float4 c = c4[kk]; Csum += c.x + c.y + c.z + c.w; }
    }

    // ---- scores: sc[jj][i] = Csum - 2 * sum_h vw[h]*rcp(1+exp(2(Wv2+Wv1)))
    for (int rep = 0; rep < 2; ++rep) {
        int i = tid + rep * 256;
        const float4* row4 = (const float4*)(Wv2 + (b * TP + i) * THP);
        float acc[4] = {0.f, 0.f, 0.f, 0.f};
#pragma unroll
        for (int kt = 0; kt < 5; ++kt) {
            float4 r0 = row4[kt * 4 + 0], r1 = row4[kt * 4 + 1];
            float4 r2 = row4[kt * 4 + 2], r3 = row4[kt * 4 + 3];
            const float4* c4 = (const float4*)(vws + kt * 16);
            float4 c0 = c4[0], c1 = c4[1], c2 = c4[2], c3 = c4[3];
#pragma unroll
            for (int jj = 0; jj < 4; ++jj) {
                const float4* w1 = (const float4*)(wv1j + jj * THP + kt * 16);
                acc[jj] += rterm4(r0, w1[0], c0) + rterm4(r1, w1[1], c1)
                         + rterm4(r2, w1[2], c2) + rterm4(r3, w1[3], c3);
            }
        }
#pragma unroll
        for (int jj = 0; jj < 4; ++jj) sc[jj * TP + i] = Csum - 2.0f * acc[jj];
    }
    __syncthreads();

    // ---- softmax over i (axis 0), one wave per jj
    {
        int jj = tid >> 6, l = tid & 63;
        float m = -1e30f;
#pragma unroll
        for (int q = 0; q < 8; ++q) m = fmaxf(m, sc[jj * TP + l + q * 64]);
#pragma unroll
        for (int s = 32; s > 0; s >>= 1) m = fmaxf(m, __shfl_xor(m, s));
        float e[8];
        float sum = 0.0f;
#pragma unroll
        for (int q = 0; q < 8; ++q) { e[q] = __expf(sc[jj * TP + l + q * 64] - m); sum += e[q]; }
#pragma unroll
        for (int s = 32; s > 0; s >>= 1) sum += __shfl_xor(sum, s);
        float inv = fast_rcp(sum);
#pragma unroll
        for (int q = 0; q < 8; ++q) sc[jj * TP + l + q * 64] = e[q] * inv;
    }
    __syncthreads();

    // ---- context: c[j,b,d] = sum_i a[i]*v[i,b,d]; thread owns d = tid
    float acc[4] = {0.f, 0.f, 0.f, 0.f};
    const float* vb = v + b * TD + tid;
    for (int i4 = 0; i4 < TP / 4; ++i4) {
        float4 a0 = ((const float4*)(sc + 0 * TP))[i4];
        float4 a1 = ((const float4*)(sc + 1 * TP))[i4];
        float4 a2 = ((const float4*)(sc + 2 * TP))[i4];
        float4 a3 = ((const float4*)(sc + 3 * TP))[i4];
#pragma unroll
        for (int u = 0; u < 4; ++u) {
            float va = vb[(i4 * 4 + u) * (TB * TD)];
            acc[0] += f4c(a0, u) * va;
            acc[1] += f4c(a1, u) * va;
            acc[2] += f4c(a2, u) * va;
            acc[3] += f4c(a3, u) * va;
        }
    }
#pragma unroll
    for (int jj = 0; jj < 4; ++jj) {
        int base = ((j0 + jj) * TB + b) * 512;
        g16[base + tid]       = (half_t)v[((j0 + jj) * TB + b) * TD + tid];
        g16[base + 256 + tid] = (half_t)acc[jj];
    }
}

// -------- MFMA gate (sigmoid(g Wg^T)*g) + GRU input projections -------------
// 128 blocks x 256 thr (4 waves); block owns 32 g-rows. Phase A:
// C1[32,512] = g16 @ Wg16B via 16x16x32 MFMA (A-frag from LDS g rows,
// B-frag straight from pre-swizzled global). sigmoid*g in-register, gated
// written back f16 in place, then phase B: xp[32,768] = gated @ Wih16B.
__global__ __launch_bounds__(256, 1) void gatexp_kernel(
    const half_t* __restrict__ g16, const half_t* __restrict__ Wg16B,
    const half_t* __restrict__ Wih16B, const float* __restrict__ bihC,
    float* __restrict__ xpf, float* __restrict__ xpb)
{
    __shared__ half_t gA[32 * 520];      // rows padded to 520 halfs (2-way-free)
    int tid = threadIdx.x;
    int r0 = blockIdx.x * 32;
    int lane = tid & 63, w = tid >> 6;
    int l15 = lane & 15, quad = lane >> 4;

    for (int e = tid; e < 2048; e += 256) {
        int row = e >> 6, c8 = e & 63;
        *(half8v*)(gA + row * 520 + c8 * 8) =
            *(const half8v*)(g16 + (r0 + row) * 512 + c8 * 8);
    }
    __syncthreads();

    // ---- phase A: gate matmul; wave w owns n-tiles w*8..w*8+8
    float4v acc[2][8];
#pragma unroll
    for (int mi = 0; mi < 2; ++mi)
#pragma unroll
        for (int nti = 0; nti < 8; ++nti) acc[mi][nti] = (float4v){0.f, 0.f, 0.f, 0.f};

    for (int kt = 0; kt < 16; ++kt) {
        half8v a0 = *(const half8v*)(gA + l15 * 520 + kt * 32 + quad * 8);
        half8v a1 = *(const half8v*)(gA + (16 + l15) * 520 + kt * 32 + quad * 8);
#pragma unroll
        for (int nti = 0; nti < 8; ++nti) {
            half8v bb = *(const half8v*)(Wg16B + (((w * 8 + nti) * 16 + kt) * 64 + lane) * 8);
            acc[0][nti] = __builtin_amdgcn_mfma_f32_16x16x32_f16(a0, bb, acc[0][nti], 0, 0, 0);
            acc[1][nti] = __builtin_amdgcn_mfma_f32_16x16x32_f16(a1, bb, acc[1][nti], 0, 0, 0);
        }
    }
    // gated = sigmoid(C1) * g  (C/D layout: col=l15 within n-tile, row=quad*4+r)
#pragma unroll
    for (int mi = 0; mi < 2; ++mi)
#pragma unroll
        for (int nti = 0; nti < 8; ++nti) {
            int colg = (w * 8 + nti) * 16 + l15;
#pragma unroll
            for (int r = 0; r < 4; ++r) {
                float gv = (float)gA[(mi * 16 + quad * 4 + r) * 520 + colg];
                acc[mi][nti][r] = fast_sigmoid(acc[mi][nti][r]) * gv;
            }
        }
    __syncthreads();   // all phase-A reads of gA done
#pragma unroll
    for (int mi = 0; mi < 2; ++mi)
#pragma unroll
        for (int nti = 0; nti < 8; ++nti) {
            int colg = (w * 8 + nti) * 16 + l15;
#pragma unroll
            for (int r = 0; r < 4; ++r)
                gA[(mi * 16 + quad * 4 + r) * 520 + colg] = (half_t)acc[mi][nti][r];
        }
    __syncthreads();

    // ---- phase B: xp = gated @ Wih16B; wave w owns n-tiles w*12..w*12+12
    float4v c2[2][12];
#pragma unroll
    for (int mi = 0; mi < 2; ++mi)
#pragma unroll
        for (int nt2 = 0; nt2 < 12; ++nt2) {
            float bv = bihC[(w * 12 + nt2) * 16 + l15];
            c2[mi][nt2] = (float4v){bv, bv, bv, bv};
        }

    for (int kt = 0; kt < 16; ++kt) {
        half8v a0 = *(const half8v*)(gA + l15 * 520 + kt * 32 + quad * 8);
        half8v a1 = *(const half8v*)(gA + (16 + l15) * 520 + kt * 32 + quad * 8);
#pragma unroll
        for (int nt2 = 0; nt2 < 12; ++nt2) {
            half8v bb = *(const half8v*)(Wih16B + (((w * 12 + nt2) * 16 + kt) * 64 + lane) * 8);
            c2[0][nt2] = __builtin_amdgcn_mfma_f32_16x16x32_f16(a0, bb, c2[0][nt2], 0, 0, 0);
            c2[1][nt2] = __builtin_amdgcn_mfma_f32_16x16x32_f16(a1, bb, c2[1][nt2], 0, 0, 0);
        }
    }
#pragma unroll
    for (int mi = 0; mi < 2; ++mi)
#pragma unroll
        for (int nt2 = 0; nt2 < 12; ++nt2) {
            int col = (w * 12 + nt2) * 16 + l15;           // tile never straddles 384
            float* dst = (col < 384) ? (xpf + col) : (xpb + col - 384);
#pragma unroll
            for (int r = 0; r < 4; ++r)
                dst[(r0 + mi * 16 + quad * 4 + r) * 384] = c2[mi][nt2][r];
        }
}

// ---------------- GRU recurrence (R3 version), one block per (dir, batch) ---
// 512 threads: (o = tid>>2, q = tid&3). w_hh f16 in VGPRs; h ping-pong f16 in
// LDS; v_dot2_f32_f16; fp32 h in register for the z*h term.
__global__ __launch_bounds__(512) void gru_kernel(
    const float* __restrict__ xpf, const float* __restrict__ xpb,
    const half_t* __restrict__ whh16,
    const float* __restrict__ bhhf, const float* __restrict__ bhhb,
    float* __restrict__ out)
{
    int tid = threadIdx.x;
    int dir = blockIdx.x >> 3;
    int b   = blockIdx.x & 7;
    const float* xp  = dir ? xpb  : xpf;
    const float* bhh = dir ? bhhb : bhhf;
    const half_t* wbase = whh16 + dir * 3 * TO * TO;

    __shared__ __align__(16) half_t hb[2][TO];

    int o = tid >> 2, q = tid & 3;

    H8 wr[4], wz[4], wn[4];
    {
        const half8v* pr = (const half8v*)(wbase + (o)          * TO + q * 32);
        const half8v* pz = (const half8v*)(wbase + (TO + o)     * TO + q * 32);
        const half8v* pn = (const half8v*)(wbase + (2 * TO + o) * TO + q * 32);
#pragma unroll
        for (int kk = 0; kk < 4; ++kk) { wr[kk].v8 = pr[kk]; wz[kk].v8 = pz[kk]; wn[kk].v8 = pn[kk]; }
    }

    float br = 0.f, bz = 0.f, bn = 0.f, h = 0.f;
    float xr = 0.f, xz = 0.f, xn = 0.f;
    if (q == 0) {
        br = bhh[o]; bz = bhh[TO + o]; bn = bhh[2 * TO + o];
        int t0 = dir ? (TP - 1) : 0;
        const float* xpt = xp + (t0 * TB + b) * 384;
        xr = xpt[o]; xz = xpt[TO + o]; xn = xpt[2 * TO + o];
    }
    if (tid < TO) hb[0][tid] = (half_t)0.0f;
    __syncthreads();

    for (int s = 0; s < TP; ++s) {
        int t = dir ? (TP - 1 - s) : s;
        int cur = s & 1;
        const half8v* h8 = (const half8v*)(&hb[cur][q * 32]);
        H8 hv[4];
#pragma unroll
        for (int kk = 0; kk < 4; ++kk) hv[kk].v8 = h8[kk];

        float ar = 0.f, az = 0.f, an = 0.f;
#pragma unroll
        for (int kk = 0; kk < 4; ++kk) {
#pragma unroll
            for (int j = 0; j < 4; ++j) {
                half2v hp = hv[kk].v2[j];
                ar = fdot2h(wr[kk].v2[j], hp, ar);
                az = fdot2h(wz[kk].v2[j], hp, az);
                an = fdot2h(wn[kk].v2[j], hp, an);
            }
        }
        ar += __shfl_xor(ar, 1); ar += __shfl_xor(ar, 2);
        az += __shfl_xor(az, 1); az += __shfl_xor(az, 2);
        an += __shfl_xor(an, 1); an += __shfl_xor(an, 2);
        if (q == 0) {
            float r = fast_sigmoid(xr + ar + br);
            float z = fast_sigmoid(xz + az + bz);
            float n = fast_tanh(xn + r * (an + bn));
            h = (1.0f - z) * n + z * h;
            hb[cur ^ 1][o] = (half_t)h;
            out[(t * TB + b) * 256 + dir * TO + o] = h;
            int sn = (s + 1 < TP) ? s + 1 : s;
            int tn = dir ? (TP - 1 - sn) : sn;
            const float* xpt = xp + (tn * TB + b) * 384;
            xr = xpt[o]; xz = xpt[TO + o]; xn = xpt[2 * TO + o];
        }
        __syncthreads();
    }
}

extern "C" void kernel_launch(void* const* d_in, const int* in_sizes, int n_in,
                              void* d_out, int out_size, void* d_ws, size_t ws_size,
                              hipStream_t stream) {
    const float* v    = (const float*)d_in[0];
    const float* Wvp1 = (const float*)d_in[1];
    const float* Wvp2 = (const float*)d_in[2];
    const float* vw   = (const float*)d_in[3];
    const float* Wg   = (const float*)d_in[4];
    const float* wihf = (const float*)d_in[5];
    const float* whhf = (const float*)d_in[6];
    const float* bihf = (const float*)d_in[7];
    const float* bhhf = (const float*)d_in[8];
    const float* wihb = (const float*)d_in[9];
    const float* whhb = (const float*)d_in[10];
    const float* bihb = (const float*)d_in[11];
    const float* bhhb = (const float*)d_in[12];

    float* ws   = (float*)d_ws;
    float* WTvp = ws;                    // 256*160      = 40960 f32
    float* bihC = WTvp + 40960;          // 768
    float* Wv1  = bihC + 768;            // 8*512*80     = 327680
    float* Wv2  = Wv1 + 327680;          // 327680
    float* xpf  = Wv2 + 327680;          // 4096*384     = 1572864
    float* xpb  = xpf + 1572864;         // 1572864
    half_t* g16    = (half_t*)(xpb + 1572864);  // 4096*512  halfs
    half_t* Wg16B  = g16 + 2097152;             // 32*16*64*8 = 262144 halfs
    half_t* Wih16B = Wg16B + 262144;            // 48*16*64*8 = 393216 halfs
    half_t* whh16  = Wih16B + 393216;           // 2*3*128*128 = 98304 halfs
    float* out  = (float*)d_out;

    // prep total idx: 40960+768+262144+393216+98304 = 795392 = 3107*256
    prep_kernel<<<3107, 256, 0, stream>>>(Wvp1, Wvp2, Wg, wihf, wihb, bihf, bihb,
                                          whhf, whhb, WTvp, bihC, Wg16B, Wih16B, whh16);
    wv12_kernel<<<4096, 256, 0, stream>>>(v, WTvp, Wv1, Wv2);
    attn_kernel<<<1024, 256, 0, stream>>>(v, Wv1, Wv2, vw, g16);
    gatexp_kernel<<<128, 256, 0, stream>>>(g16, Wg16B, Wih16B, bihC, xpf, xpb);
    gru_kernel<<<16, 512, 0, stream>>>(xpf, xpb, whh16, bhhf, bhhb, out);
}